// Round 10
// baseline (137.060 us; speedup 1.0000x reference)
//
#include <hip/hip_runtime.h>
#include <math.h>

#define B_ 8
#define T_ 2048
#define D_ 1024
#define HS_ 64

typedef _Float16 f16x8 __attribute__((ext_vector_type(8)));
typedef _Float16 f16x4 __attribute__((ext_vector_type(4)));
typedef float f32x4 __attribute__((ext_vector_type(4)));

typedef __attribute__((address_space(3))) void       lds_void;
typedef const __attribute__((address_space(1))) void gbl_void;
__device__ static inline void async_ld16(gbl_void* g, lds_void* l) {
    // 16 B per lane, HW dest = lds_base + lane*16 (wave-uniform base)
    __builtin_amdgcn_global_load_lds(g, l, 16, 0, 0);
}

// ---------------------------------------------------------------------------
// ws layout (f16 elements unless noted).  qf/kf/vf are FRAGMENT-PACKED, unit
// = 512 f16 = 1 KB = one MFMA operand fragment for a 64-lane wave:
//   qf: unit (b, qt, w, s)  elem = q[b][qt*64 + w*16 + lid][s*32 + quad*8 + e]
//   kf: unit (b, kt, nt, s) elem = k[b][kt*64 + nt*16 + lid][s*32 + quad*8 + e]
//   vf: unit (b, kt, ht, s) elem = v[b][kt*64 + s*32 + quad*8 + e][ht*16 + lid]
//   (lane = quad*16 + lid; unit offset = (((b*32+t64)*4 + u)*2 + s)*512)
//   qf    : @ 0          (1,048,576)
//   kf    : @ 1,048,576
//   vf    : @ 2,097,152
//   Wfrag : @ 3,145,728  (196,608)
//   Op    : @ 3,342,336  (4,718,592)
//   ml    : @ f16-idx 8,060,928  ([1152][128] f32)
// ---------------------------------------------------------------------------

// Stage 0: Wq|Wk|Wv (fp32 [1024][64]) -> Wfrag (f16, MFMA-fragment order)
__global__ __launch_bounds__(256) void wt_kernel(
    const float* __restrict__ Wq, const float* __restrict__ Wk,
    const float* __restrict__ Wv, _Float16* __restrict__ Wfrag)
{
    __shared__ _Float16 Tt[64][72];   // Tt[h][k_local]
    const int my = blockIdx.y;        // matrix 0,1,2
    const float* W = (my == 0) ? Wq : (my == 1) ? Wk : Wv;
    const int t  = threadIdx.x;
    const int kb = blockIdx.x;        // 64-k block
    const int k0 = kb * 64;
    {
        const int r = t >> 2, c0 = (t & 3) * 16;   // r = k row, c0 = h base
#pragma unroll
        for (int i = 0; i < 4; ++i) {
            float4 w = *(const float4*)&W[(size_t)(k0 + r) * HS_ + c0 + i * 4];
            Tt[c0 + i * 4 + 0][r] = (_Float16)w.x;
            Tt[c0 + i * 4 + 1][r] = (_Float16)w.y;
            Tt[c0 + i * 4 + 2][r] = (_Float16)w.z;
            Tt[c0 + i * 4 + 3][r] = (_Float16)w.w;
        }
    }
    __syncthreads();
    {
        const int lane = t & 63, j = t >> 6;       // j = n-tile within matrix
        const int lid = lane & 15, quad = lane >> 4;
        const int c = kb >> 1, shalf = kb & 1;
        const int nt = my * 4 + j;
#pragma unroll
        for (int s2 = 0; s2 < 2; ++s2) {
            const int u = (c * 12 + nt) * 4 + shalf * 2 + s2;
            *(int4*)&Wfrag[(size_t)u * 512 + lane * 8] =
                *(int4*)&Tt[j * 16 + lid][s2 * 32 + quad * 8];
        }
    }
}

// ---------------------------------------------------------------------------
// Stage 1: QKV projection (main loop unchanged from R7).  Epilogue now emits
// qf/kf/vf in attn's fragment order (same store count, different addresses).
// Block m-tile = 32 rows = half a 64-token tile: kt = tl0>>6, half = bit5.
// ---------------------------------------------------------------------------
__global__ __launch_bounds__(256, 2) void qkv_kernel(
    const float* __restrict__ x, const _Float16* __restrict__ Wfrag,
    _Float16* __restrict__ qf, _Float16* __restrict__ kf,
    _Float16* __restrict__ vf)
{
    __shared__ __align__(16) char smem[65792];        // Xs 16640 | Ws 49152
    _Float16* Ws = (_Float16*)(smem + 16640);
    _Float16 (*CsH)[200] = (_Float16(*)[200])smem;     // epilogue overlay

    const int t    = threadIdx.x;
    const int m0   = blockIdx.x * 32;
    const int lane = t & 63, wave = t >> 6;
    const int lid  = lane & 15, quad = lane >> 4;
    const int mt   = wave & 1;          // row group (16 rows)
    const int nh   = wave >> 1;         // n-half (6 n-tiles)

    f32x4 acc[6];
#pragma unroll
    for (int i = 0; i < 6; ++i) acc[i] = f32x4{0.f, 0.f, 0.f, 0.f};

    for (int c = 0; c < 8; ++c) {
        const int kc = c * 128;
        __syncthreads();   // previous chunk's LDS reads complete
#pragma unroll
        for (int i = 0; i < 4; ++i) {
            const int xu = wave * 4 + i;
            const float* g = x + (size_t)(m0 + xu * 2 + (lane >> 5)) * D_
                             + kc + (lane & 31) * 4;
            async_ld16((gbl_void*)g, (lds_void*)(smem + xu * 1040));
        }
#pragma unroll
        for (int i = 0; i < 12; ++i) {
            const int v = wave * 12 + i;
            const _Float16* g = Wfrag + (size_t)(c * 48 + v) * 512 + lane * 8;
            async_ld16((gbl_void*)g, (lds_void*)&Ws[v * 512]);
        }
        __syncthreads();   // vmcnt(0) drain => DMA complete

#pragma unroll
        for (int s = 0; s < 4; ++s) {
            const int row = mt * 16 + lid;
            const int xoff = (row >> 1) * 1040 + (row & 1) * 512
                             + (s * 32 + quad * 8) * 4;
            const f32x4 alo = *(const f32x4*)(smem + xoff);
            const f32x4 ahi = *(const f32x4*)(smem + xoff + 16);
            f16x8 a;
#pragma unroll
            for (int j = 0; j < 4; ++j) {
                a[j]     = (_Float16)alo[j];
                a[4 + j] = (_Float16)ahi[j];
            }
#pragma unroll
            for (int j = 0; j < 6; ++j) {
                const int v = (nh * 6 + j) * 4 + s;
                const f16x8 b = *(const f16x8*)&Ws[v * 512 + lane * 8];
                acc[j] = __builtin_amdgcn_mfma_f32_16x16x32_f16(a, b, acc[j], 0, 0, 0);
            }
        }
    }
    __syncthreads();   // all staging reads done before overlay writes

#pragma unroll
    for (int j = 0; j < 6; ++j)
#pragma unroll
        for (int r = 0; r < 4; ++r)
            CsH[mt * 16 + quad * 4 + r][(nh * 6 + j) * 16 + lid] = (_Float16)acc[j][r];
    __syncthreads();

    const int bi = m0 >> 11, tl0 = m0 & 2047;
    const int kt = tl0 >> 6, half = (tl0 >> 5) & 1;
    {
        // Q/K frag units: u = (s<<1)|wh ; one int4 each for q and k
        const int u  = t >> 6;
        const int wh = u & 1, s = u >> 1;
        const size_t base = ((((size_t)bi * 32 + kt) * 4 + (2 * half + wh)) * 2 + s) * 512
                            + lane * 8;
        *(int4*)&qf[base] = *(int4*)&CsH[wh * 16 + lid][s * 32 + quad * 8];
        *(int4*)&kf[base] = *(int4*)&CsH[wh * 16 + lid][64 + s * 32 + quad * 8];
    }
    {
        // V frag units: (ht = t>>6, s = half); transpose-gather then int4
        const int ht = t >> 6;
        _Float16 tmp[8];
#pragma unroll
        for (int e = 0; e < 8; ++e) tmp[e] = CsH[quad * 8 + e][128 + ht * 16 + lid];
        const size_t vb = ((((size_t)bi * 32 + kt) * 4 + ht) * 2 + half) * 512 + lane * 8;
        *(int4*)&vf[vb] = *(int4*)&tmp[0];
    }
}

// ---------------------------------------------------------------------------
// Stage 2: causal flash attention.  Frag-packed inputs; K/V staged via
// contiguous 1 KB global_load_lds into frag-linear LDS (conflict-free
// lane*16 reads).  2 k-tiles (128 keys) per barrier pair: one combined
// softmax (2 shfls), then P-pack + PV per sub-tile.  S^T = K.Q^T so softmax
// rows are per-lane.  Split-K chunks of 4 k-tiles, grid (144, 8) as before.
// LDS ~50 KB -> 3 blocks/CU.
// ---------------------------------------------------------------------------
__global__ __launch_bounds__(256, 3) void attn_kernel(
    const _Float16* __restrict__ qf, const _Float16* __restrict__ kf,
    const _Float16* __restrict__ vf, _Float16* __restrict__ Opart,
    float* __restrict__ ml, float* __restrict__ out)
{
    __shared__ __align__(16) _Float16 Qs[8 * 512];      // 8 KB
    __shared__ __align__(16) _Float16 KV[32 * 512];     // 32 KB: [pair-tile][u2]
    __shared__ __align__(16) _Float16 Pw[4][16][72];    // 9.2 KB wave-private

    const int p = blockIdx.x, b = blockIdx.y;
    int g = 0;
    while (p >= 2 * (g + 1) * (g + 2)) ++g;
    const int rem = p - 2 * g * (g + 1);
    const int qi  = 4 * g + rem / (g + 1);
    const int cc  = rem % (g + 1);
    const int kts = cc * 4;
    const int kte = min(qi + 1, kts + 4);

    const int q0 = qi * 64;
    const size_t bT = (size_t)b * T_;
    const int t = threadIdx.x;
    const int lane = t & 63, wave = t >> 6;
    const int lid  = lane & 15, quad = lane >> 4;

    // stage Q fragments (async, contiguous 1 KB units; wave w stages its own)
    {
        const _Float16* gq = qf + ((((size_t)b * 32 + qi) * 4 + wave) * 2) * 512 + lane * 8;
        async_ld16((gbl_void*)gq,         (lds_void*)&Qs[(wave * 2 + 0) * 512]);
        async_ld16((gbl_void*)(gq + 512), (lds_void*)&Qs[(wave * 2 + 1) * 512]);
    }
    __syncthreads();
    const f16x8 aq0 = *(const f16x8*)&Qs[(wave * 2 + 0) * 512 + lane * 8];
    const f16x8 aq1 = *(const f16x8*)&Qs[(wave * 2 + 1) * 512 + lane * 8];

    f32x4 o[4];          // O^T: o[ht][r] = O[q=lid][h=ht*16+quad*4+r]
#pragma unroll
    for (int i = 0; i < 4; ++i) o[i] = f32x4{0.f, 0.f, 0.f, 0.f};
    float mcur = -1e30f, lcur = 0.f;

    const float SC = 0.125f * 1.44269504088896f;   // HS^-0.5 * log2(e)
    const int qg = q0 + wave * 16 + lid;

    for (int kp = kts; kp < kte; kp += 2) {
        const int ntiles = min(2, kte - kp);
        __syncthreads();   // previous pair's LDS reads complete
        // stage K/V: unit u = wave*(ntiles*4) + i; decode j|u2; 1 KB each
#pragma unroll
        for (int i = 0; i < 8; ++i) {
            if (i < ntiles * 4) {
                const int u  = wave * (ntiles * 4) + i;
                const int j  = u >> 4, u2 = u & 15;
                const int kt = kp + j;
                const int s  = u2 & 1;
                const _Float16* gsrc;
                if (u2 < 8)
                    gsrc = kf + ((((size_t)b * 32 + kt) * 4 + (u2 >> 1)) * 2 + s) * 512;
                else
                    gsrc = vf + ((((size_t)b * 32 + kt) * 4 + ((u2 - 8) >> 1)) * 2 + s) * 512;
                async_ld16((gbl_void*)(gsrc + lane * 8), (lds_void*)&KV[u * 512]);
            }
        }
        __syncthreads();   // drain => DMA complete

        // S^T = K.Q^T for both sub-tiles
        float sv[2][4][4];
#pragma unroll
        for (int j = 0; j < 2; ++j)
#pragma unroll
            for (int nt = 0; nt < 4; ++nt)
#pragma unroll
                for (int r = 0; r < 4; ++r) sv[j][nt][r] = -1e30f;
#pragma unroll
        for (int j = 0; j < 2; ++j) {
            if (j < ntiles) {
                const int kt = kp + j;
                const bool diag = (kt == qi);
                const int k0 = kt * 64;
#pragma unroll
                for (int nt = 0; nt < 4; ++nt) {
                    const f16x8 ka0 = *(const f16x8*)&KV[(j * 16 + nt * 2 + 0) * 512 + lane * 8];
                    const f16x8 ka1 = *(const f16x8*)&KV[(j * 16 + nt * 2 + 1) * 512 + lane * 8];
                    f32x4 s = f32x4{0.f, 0.f, 0.f, 0.f};
                    s = __builtin_amdgcn_mfma_f32_16x16x32_f16(ka0, aq0, s, 0, 0, 0);
                    s = __builtin_amdgcn_mfma_f32_16x16x32_f16(ka1, aq1, s, 0, 0, 0);
#pragma unroll
                    for (int r = 0; r < 4; ++r) {
                        float v = s[r] * SC;
                        if (diag && (k0 + nt * 16 + quad * 4 + r > qg)) v = -1e30f;
                        sv[j][nt][r] = v;
                    }
                }
            }
        }

        // combined per-lane softmax over up to 128 keys: 2 shfls total
        float pm = -1e30f;
#pragma unroll
        for (int j = 0; j < 2; ++j)
#pragma unroll
            for (int nt = 0; nt < 4; ++nt)
#pragma unroll
                for (int r = 0; r < 4; ++r) pm = fmaxf(pm, sv[j][nt][r]);
        pm = fmaxf(pm, __shfl_xor(pm, 16, 64));
        pm = fmaxf(pm, __shfl_xor(pm, 32, 64));
        const float mn = fmaxf(mcur, pm);
        const float al = exp2f(mcur - mn);
        mcur = mn;
        float rs = 0.f;
#pragma unroll
        for (int j = 0; j < 2; ++j)
#pragma unroll
            for (int nt = 0; nt < 4; ++nt)
#pragma unroll
                for (int r = 0; r < 4; ++r) {
                    const float pv = exp2f(sv[j][nt][r] - mn);
                    sv[j][nt][r] = pv;
                    rs += pv;
                }
        rs += __shfl_xor(rs, 16, 64);
        rs += __shfl_xor(rs, 32, 64);
        lcur = lcur * al + rs;
#pragma unroll
        for (int ht = 0; ht < 4; ++ht)
#pragma unroll
            for (int r = 0; r < 4; ++r) o[ht][r] *= al;

        // P-pack + PV per sub-tile (wave-private, no barriers)
        for (int j = 0; j < ntiles; ++j) {
#pragma unroll
            for (int nt = 0; nt < 4; ++nt) {
                f16x4 p4;
#pragma unroll
                for (int r = 0; r < 4; ++r) p4[r] = (_Float16)sv[j][nt][r];
                *(f16x4*)&Pw[wave][lid][nt * 16 + quad * 4] = p4;
            }
            const f16x8 bp0 = *(const f16x8*)&Pw[wave][lid][quad * 8];
            const f16x8 bp1 = *(const f16x8*)&Pw[wave][lid][32 + quad * 8];
#pragma unroll
            for (int ht = 0; ht < 4; ++ht) {
                const f16x8 va0 = *(const f16x8*)&KV[(j * 16 + 8 + ht * 2 + 0) * 512 + lane * 8];
                const f16x8 va1 = *(const f16x8*)&KV[(j * 16 + 8 + ht * 2 + 1) * 512 + lane * 8];
                o[ht] = __builtin_amdgcn_mfma_f32_16x16x32_f16(va0, bp0, o[ht], 0, 0, 0);
                o[ht] = __builtin_amdgcn_mfma_f32_16x16x32_f16(va1, bp1, o[ht], 0, 0, 0);
            }
        }
    }

    // ---- epilogue: transpose O^T through the dead wave-private P slice ----
    if (g == 0) {
        const float inv = 1.0f / lcur;       // per-lane (q = lid)
        float* Osc = (float*)&Pw[wave][0][0];   // 576 floats = 16 x 36
        const int qr = lane >> 2, hc = (lane & 3) * 8;
#pragma unroll
        for (int half = 0; half < 2; ++half) {
#pragma unroll
            for (int hh = 0; hh < 2; ++hh) {
                const int ht = half * 2 + hh;
                f32x4 ov;
#pragma unroll
                for (int r = 0; r < 4; ++r) ov[r] = o[ht][r] * inv;
                *(f32x4*)&Osc[lid * 36 + hh * 16 + quad * 4] = ov;
            }
            const f32x4 r0 = *(const f32x4*)&Osc[qr * 36 + hc];
            const f32x4 r1 = *(const f32x4*)&Osc[qr * 36 + hc + 4];
            float* op = &out[(bT + q0 + wave * 16 + qr) * HS_ + half * 32 + hc];
            *(f32x4*)op       = r0;
            *(f32x4*)(op + 4) = r1;
        }
    } else {
        _Float16* Ph = &Pw[wave][0][0];      // f16 [16][72]
#pragma unroll
        for (int ht = 0; ht < 4; ++ht) {
            f16x4 t4;
#pragma unroll
            for (int r = 0; r < 4; ++r) t4[r] = (_Float16)o[ht][r];
            *(f16x4*)&Ph[lid * 72 + ht * 16 + quad * 4] = t4;
        }
        const int slot = b * 144 + p;
        _Float16* Ob = Opart + (size_t)slot * 4096;
        const int qr = lane >> 2, hc = (lane & 3) * 16;
        const int4 w0 = *(const int4*)&Ph[qr * 72 + hc];
        const int4 w1 = *(const int4*)&Ph[qr * 72 + hc + 8];
        *(int4*)&Ob[(wave * 16 + qr) * 64 + hc]     = w0;
        *(int4*)&Ob[(wave * 16 + qr) * 64 + hc + 8] = w1;
        if (lane < 16) {
            ml[(size_t)slot * 128 + wave * 16 + lane]      = mcur;
            ml[(size_t)slot * 128 + 64 + wave * 16 + lane] = lcur;
        }
    }
}

// ---------------------------------------------------------------------------
// Stage 3: combine partials for q-tiles with >=2 chunks (qi >= 4).
// (unchanged)
// ---------------------------------------------------------------------------
__global__ __launch_bounds__(256) void combine_kernel(
    const _Float16* __restrict__ Opart, const float* __restrict__ ml,
    float* __restrict__ out)
{
    const int qi = 4 + blockIdx.x, b = blockIdx.y;
    const int g = qi >> 2, nc = g + 1;
    const int poff = 2 * g * (g + 1) + (qi & 3) * (g + 1);
    const int t = threadIdx.x, row = t >> 2, c0 = (t & 3) * 16;

    float mv[8], M = -1e30f;
#pragma unroll
    for (int cc = 0; cc < 8; ++cc) {
        mv[cc] = (cc < nc) ? ml[(size_t)(b * 144 + poff + cc) * 128 + row] : -1e30f;
        M = fmaxf(M, mv[cc]);
    }
    float L = 0.f, accv[16];
#pragma unroll
    for (int j = 0; j < 16; ++j) accv[j] = 0.f;
#pragma unroll
    for (int cc = 0; cc < 8; ++cc) {
        if (cc < nc) {   // nc is block-uniform: no divergence
            const int slot = b * 144 + poff + cc;
            const float w = exp2f(mv[cc] - M);
            L += ml[(size_t)slot * 128 + 64 + row] * w;
            f16x8 o0 = *(const f16x8*)&Opart[(size_t)slot * 4096 + row * 64 + c0];
            f16x8 o1 = *(const f16x8*)&Opart[(size_t)slot * 4096 + row * 64 + c0 + 8];
#pragma unroll
            for (int j = 0; j < 8; ++j) {
                accv[j]     += w * (float)o0[j];
                accv[8 + j] += w * (float)o1[j];
            }
        }
    }
    const float inv = 1.0f / L;
    const size_t obase = ((size_t)b * T_ + qi * 64 + row) * HS_ + c0;
#pragma unroll
    for (int u = 0; u < 4; ++u) {
        float4 r4;
        r4.x = accv[u * 4 + 0] * inv;
        r4.y = accv[u * 4 + 1] * inv;
        r4.z = accv[u * 4 + 2] * inv;
        r4.w = accv[u * 4 + 3] * inv;
        *(float4*)&out[obase + u * 4] = r4;
    }
}

// ---------------------------------------------------------------------------
extern "C" void kernel_launch(void* const* d_in, const int* in_sizes, int n_in,
                              void* d_out, int out_size, void* d_ws, size_t ws_size,
                              hipStream_t stream)
{
    const float* x  = (const float*)d_in[0];
    const float* Wq = (const float*)d_in[1];
    const float* Wk = (const float*)d_in[2];
    const float* Wv = (const float*)d_in[3];
    float* out = (float*)d_out;

    _Float16* w     = (_Float16*)d_ws;
    _Float16* qf    = w;
    _Float16* kf    = w + 1048576;
    _Float16* vf    = w + 2097152;
    _Float16* Wfrag = w + 3145728;
    _Float16* Op    = w + 3342336;            // + 196,608
    float*    ml    = (float*)(w + 8060928);  // Op + 4,718,592

    wt_kernel<<<dim3(16, 3), 256, 0, stream>>>(Wq, Wk, Wv, Wfrag);
    qkv_kernel<<<512, 256, 0, stream>>>(x, Wfrag, qf, kf, vf);
    attn_kernel<<<dim3(144, 8), 256, 0, stream>>>(qf, kf, vf, Op, ml, out);
    combine_kernel<<<dim3(28, 8), 256, 0, stream>>>(Op, ml, out);
}